// Round 1
// baseline (323.313 us; speedup 1.0000x reference)
//
#include <hip/hip_runtime.h>
#include <stdint.h>

// Problem constants
#define B_ 16
#define C_ 512
#define T_ 4000
#define TPAD 4096   // hT rows padded per batch so tail N-tiles read in-bounds

typedef float f32x4 __attribute__((ext_vector_type(4)));
typedef __bf16 bf16x8 __attribute__((ext_vector_type(8)));

// ---------- helpers ----------
__device__ inline unsigned short f2b(float f) {   // fp32 -> bf16 bits, RNE
  uint32_t u = __builtin_bit_cast(uint32_t, f);
  u = (u + 0x7fffu + ((u >> 16) & 1u)) >> 16;
  return (unsigned short)u;
}
__device__ inline float b2f(unsigned short h) {
  uint32_t u = ((uint32_t)h) << 16;
  return __builtin_bit_cast(float, u);
}
__device__ inline void gl_lds16(const void* g, void* s) {
  __builtin_amdgcn_global_load_lds(
      (const __attribute__((address_space(1))) uint32_t*)g,
      (__attribute__((address_space(3))) uint32_t*)s, 16, 0, 0);
}

// ws float layout: [0..15] sum, [16..31] sumsq, [32..47] mean, [48..63] rstd,
//                  [64..575] s1[o], [576..1087] s2[o]
// byte 8192  : Wp bf16 [512][512]  (pw * gln_gamma, row-major o,c)
// byte 1<<20 : hT bf16 [16][4096][512]  (t-major, c contiguous)

__global__ void k_init(float* wsf) {
  int i = threadIdx.x;
  if (i < 32) wsf[i] = 0.f;
}

// one block per output row o: W'[o,c] = pw*gamma (bf16), s1[o]=sum W', s2[o]=sum pw*beta
__global__ __launch_bounds__(64) void k_prepw(const float* __restrict__ pw,
                                              const float* __restrict__ gamma,
                                              const float* __restrict__ beta,
                                              unsigned short* __restrict__ Wp,
                                              float* __restrict__ wsf) {
  int o = blockIdx.x, l = threadIdx.x;
  float a1 = 0.f, a2 = 0.f;
  for (int j = 0; j < 8; ++j) {
    int c = j * 64 + l;
    float wv = pw[o * 512 + c];
    unsigned short wb = f2b(wv * gamma[c]);
    Wp[o * 512 + c] = wb;
    a1 += b2f(wb);              // consistent with bf16 weights used in GEMM
    a2 += wv * beta[c];
  }
  for (int s = 32; s > 0; s >>= 1) { a1 += __shfl_down(a1, s); a2 += __shfl_down(a2, s); }
  if (l == 0) { wsf[64 + o] = a1; wsf[576 + o] = a2; }
}

// fused ReLU+BN+dwconv3+PReLU; writes hT[b][t][c] bf16 (transposed) + stats atomics.
// block = (t-tile of 64, b). 512 threads: lane = t within tile, wave = c stride 8.
__global__ __launch_bounds__(512) void k_front(const float* __restrict__ x,
    const float* __restrict__ bng, const float* __restrict__ bnb,
    const float* __restrict__ bnm, const float* __restrict__ bnv,
    const float* __restrict__ dw, const float* __restrict__ pa,
    unsigned short* __restrict__ hT, float* __restrict__ wsf) {
  __shared__ unsigned short hs[64 * 512];   // 64 KB, XOR-swizzled to avoid bank conflicts
  int tid = threadIdx.x;
  int l = tid & 63, w = tid >> 6;
  int b = blockIdx.y;
  int t0 = blockIdx.x * 64;
  int t = t0 + l;
  float alpha = pa[0];
  float sum = 0.f, sq = 0.f;
  for (int ci = 0; ci < 64; ++ci) {
    int c = ci * 8 + w;
    float sc = bng[c] * rsqrtf(bnv[c] + 1e-5f);
    float bi = bnb[c] - bnm[c] * sc;
    float w0 = dw[3 * c], w1 = dw[3 * c + 1], w2 = dw[3 * c + 2];
    const float* xr = x + ((size_t)b * C_ + c) * T_;
    float ul = 0.f, uc = 0.f, ur = 0.f;    // conv pad = 0 (post-BN zeros)
    if (t >= 1 && t <= T_) { float v = xr[t - 1]; ul = fmaxf(v, 0.f) * sc + bi; }
    if (t < T_)            { float v = xr[t];     uc = fmaxf(v, 0.f) * sc + bi; }
    if (t + 1 < T_)        { float v = xr[t + 1]; ur = fmaxf(v, 0.f) * sc + bi; }
    float h = w0 * ul + w1 * uc + w2 * ur;
    float p = h >= 0.f ? h : alpha * h;
    if (t < T_) { sum += p; sq += p * p; } else { p = 0.f; }
    // swizzle: elem = t*512 + (c ^ ((t&31)<<1)) -> conflict-free u16 writes
    hs[l * 512 + (c ^ ((l & 31) << 1))] = f2b(p);
  }
  for (int s = 32; s > 0; s >>= 1) { sum += __shfl_down(sum, s); sq += __shfl_down(sq, s); }
  if (l == 0) { atomicAdd(&wsf[b], sum); atomicAdd(&wsf[16 + b], sq); }
  __syncthreads();
  // copy LDS tile -> global hT[b][t0+t][c], un-swizzling; dword granularity, coalesced
  const uint32_t* hs32 = (const uint32_t*)hs;
  uint32_t* dst = (uint32_t*)hT + ((size_t)b * TPAD + t0) * 256;
  for (int r8 = 0; r8 < 8; ++r8) {
    int tr = r8 * 8 + w;
    for (int k = 0; k < 4; ++k) {
      int d = l + 64 * k;
      dst[tr * 256 + d] = hs32[tr * 256 + (d ^ (tr & 31))];
    }
  }
}

__global__ void k_finalize(float* wsf) {
  int b = threadIdx.x;
  if (b < 16) {
    float n = (float)C_ * (float)T_;
    float mean = wsf[b] / n;
    float var = wsf[16 + b] / n - mean * mean;
    wsf[32 + b] = mean;
    wsf[48 + b] = rsqrtf(fmaxf(var, 0.f) + 1e-8f);
  }
}

// GEMM: out[b,o,t] = rstd[b]*sum_c W'[o,c]*h[b,c,t] + (s2[o]-mean*rstd*s1[o]) + x[b,o,t]
// 128x128 tile, BK=64, 4 waves (2x2), single 32KB LDS buffer, T2 XOR swizzle,
// global_load_lds w16 staging with pre-swizzled global source.
__global__ __launch_bounds__(256) void k_gemm(const unsigned short* __restrict__ Wp,
    const unsigned short* __restrict__ hT, const float* __restrict__ x,
    const float* __restrict__ wsf, float* __restrict__ out) {
  __shared__ unsigned short As[128 * 64];   // [o][k] swizzled, 16 KB
  __shared__ unsigned short Bs[128 * 64];   // [t][k] swizzled, 16 KB
  int tid = threadIdx.x;
  int l = tid & 63, w = tid >> 6;
  int nb = blockIdx.x, mb = blockIdx.y, b = blockIdx.z;
  int wm = w >> 1, wn = w & 1;
  const unsigned short* hTb = hT + (size_t)b * TPAD * 512;

  // per-thread staging source offsets (element units). LDS slot i holds
  // row=i>>3, 16B-slot s=i&7, global k-slot = s ^ (row&7)  (inverse swizzle on source)
  int aoff[4], boff[4];
#pragma unroll
  for (int r = 0; r < 4; ++r) {
    int i = r * 256 + tid;
    int row = i >> 3, s = i & 7;
    int ksl = (s ^ (row & 7)) << 3;
    aoff[r] = (mb * 128 + row) * 512 + ksl;
    boff[r] = (nb * 128 + row) * 512 + ksl;
  }

  f32x4 acc[4][4] = {};
  for (int ks = 0; ks < 8; ++ks) {
    int kofs = ks * 64;
#pragma unroll
    for (int r = 0; r < 4; ++r) {
      int i = r * 256 + tid;
      gl_lds16(Wp + aoff[r] + kofs, As + i * 8);
      gl_lds16(hTb + boff[r] + kofs, Bs + i * 8);
    }
    __syncthreads();   // drains vmcnt(0) -> staged tile visible
#pragma unroll
    for (int kk = 0; kk < 2; ++kk) {
      bf16x8 af[4], bfr[4];
#pragma unroll
      for (int fm = 0; fm < 4; ++fm) {
        int row = wm * 64 + fm * 16 + (l & 15);
        int slot = ((l >> 4) + kk * 4) ^ (row & 7);
        af[fm] = *(const bf16x8*)(As + row * 64 + slot * 8);
      }
#pragma unroll
      for (int fn = 0; fn < 4; ++fn) {
        int row = wn * 64 + fn * 16 + (l & 15);
        int slot = ((l >> 4) + kk * 4) ^ (row & 7);
        bfr[fn] = *(const bf16x8*)(Bs + row * 64 + slot * 8);
      }
#pragma unroll
      for (int fm = 0; fm < 4; ++fm)
#pragma unroll
        for (int fn = 0; fn < 4; ++fn)
          acc[fm][fn] = __builtin_amdgcn_mfma_f32_16x16x32_bf16(af[fm], bfr[fn], acc[fm][fn], 0, 0, 0);
    }
    __syncthreads();   // all waves done reading before next stage overwrites
  }

  float mean = wsf[32 + b], rstd = wsf[48 + b];
  float mr = mean * rstd;
#pragma unroll
  for (int fm = 0; fm < 4; ++fm) {
    int o0 = mb * 128 + wm * 64 + fm * 16 + ((l >> 4) << 2);
    float bias[4];
#pragma unroll
    for (int j = 0; j < 4; ++j) {
      int o = o0 + j;
      bias[j] = wsf[576 + o] - mr * wsf[64 + o];
    }
#pragma unroll
    for (int fn = 0; fn < 4; ++fn) {
      int t = nb * 128 + wn * 64 + fn * 16 + (l & 15);
      if (t < T_) {
#pragma unroll
        for (int j = 0; j < 4; ++j) {
          int o = o0 + j;
          size_t idx = ((size_t)b * C_ + o) * T_ + t;
          out[idx] = rstd * acc[fm][fn][j] + bias[j] + x[idx];
        }
      }
    }
  }
}

extern "C" void kernel_launch(void* const* d_in, const int* in_sizes, int n_in,
                              void* d_out, int out_size, void* d_ws, size_t ws_size,
                              hipStream_t stream) {
  const float* x   = (const float*)d_in[0];
  const float* bng = (const float*)d_in[1];
  const float* bnb = (const float*)d_in[2];
  const float* bnm = (const float*)d_in[3];
  const float* bnv = (const float*)d_in[4];
  const float* dw  = (const float*)d_in[5];
  const float* pa  = (const float*)d_in[6];
  const float* gg  = (const float*)d_in[7];
  const float* gb  = (const float*)d_in[8];
  const float* pw  = (const float*)d_in[9];
  float* out = (float*)d_out;
  float* wsf = (float*)d_ws;
  unsigned short* Wp = (unsigned short*)((char*)d_ws + 8192);
  unsigned short* hT = (unsigned short*)((char*)d_ws + (1 << 20));

  k_init<<<dim3(1), dim3(64), 0, stream>>>(wsf);
  k_prepw<<<dim3(512), dim3(64), 0, stream>>>(pw, gg, gb, Wp, wsf);
  k_front<<<dim3(63, 16), dim3(512), 0, stream>>>(x, bng, bnb, bnm, bnv, dw, pa, hT, wsf);
  k_finalize<<<dim3(1), dim3(64), 0, stream>>>(wsf);
  k_gemm<<<dim3(32, 4, 16), dim3(256), 0, stream>>>(Wp, hT, x, wsf, out);
}

// Round 2
// 156.426 us; speedup vs baseline: 2.0669x; 2.0669x over previous
//
#include <hip/hip_runtime.h>
#include <stdint.h>

// Problem constants
#define B_ 16
#define C_ 512
#define T_ 4000
#define TPAD 4096   // hT rows padded per batch so tail N-tiles read in-bounds

typedef float f32x4 __attribute__((ext_vector_type(4)));
typedef __bf16 bf16x8 __attribute__((ext_vector_type(8)));

// ---------- helpers ----------
__device__ inline unsigned short f2b(float f) {   // fp32 -> bf16 bits, RNE
  uint32_t u = __builtin_bit_cast(uint32_t, f);
  u = (u + 0x7fffu + ((u >> 16) & 1u)) >> 16;
  return (unsigned short)u;
}
__device__ inline float b2f(unsigned short h) {
  uint32_t u = ((uint32_t)h) << 16;
  return __builtin_bit_cast(float, u);
}
__device__ inline void gl_lds16(const void* g, void* s) {
  __builtin_amdgcn_global_load_lds(
      (const __attribute__((address_space(1))) uint32_t*)g,
      (__attribute__((address_space(3))) uint32_t*)s, 16, 0, 0);
}

// ws float layout: [0..15] sum, [16..31] sumsq, [32..47] mean, [48..63] rstd,
//                  [64..575] s1[o], [576..1087] s2[o]
// byte 8192  : Wp bf16 [512][512]  (pw * gln_gamma, row-major o,c)
// byte 1<<20 : hT bf16 [16][4096][512]  (t-major, c contiguous)

__global__ void k_init(float* wsf) {
  int i = threadIdx.x;
  if (i < 32) wsf[i] = 0.f;
}

// one block per output row o: W'[o,c] = pw*gamma (bf16), s1[o]=sum W', s2[o]=sum pw*beta
__global__ __launch_bounds__(64) void k_prepw(const float* __restrict__ pw,
                                              const float* __restrict__ gamma,
                                              const float* __restrict__ beta,
                                              unsigned short* __restrict__ Wp,
                                              float* __restrict__ wsf) {
  int o = blockIdx.x, l = threadIdx.x;
  float a1 = 0.f, a2 = 0.f;
  for (int j = 0; j < 8; ++j) {
    int c = j * 64 + l;
    float wv = pw[o * 512 + c];
    unsigned short wb = f2b(wv * gamma[c]);
    Wp[o * 512 + c] = wb;
    a1 += b2f(wb);              // consistent with bf16 weights used in GEMM
    a2 += wv * beta[c];
  }
  for (int s = 32; s > 0; s >>= 1) { a1 += __shfl_down(a1, s); a2 += __shfl_down(a2, s); }
  if (l == 0) { wsf[64 + o] = a1; wsf[576 + o] = a2; }
}

// fused ReLU+BN+dwconv3+PReLU; writes hT[b][t][c] bf16 (transposed) + stats.
// Block: 512 thr = 8 waves. Tile: 256 t x 128 c. Lane l owns t = t0+4l..4l+3
// (one float4 x load per channel); wave w owns channels w*16..w*16+15.
// LDS hs[t][c] bf16 with 16B-granular XOR swizzle (c ^ ((l&7)<<3)):
// conflict-free b128 reads for the coalesced global store.
__global__ __launch_bounds__(512) void k_front(const float* __restrict__ x,
    const float* __restrict__ bng, const float* __restrict__ bnb,
    const float* __restrict__ bnm, const float* __restrict__ bnv,
    const float* __restrict__ dw, const float* __restrict__ pa,
    unsigned short* __restrict__ hT, float* __restrict__ wsf) {
  __shared__ unsigned short hs[256 * 128] __attribute__((aligned(16)));  // 64 KB
  __shared__ float psc[128], pbi[128], pq0[128], pq1[128], pq2[128];
  __shared__ float partial[16];
  int tid = threadIdx.x;
  int l = tid & 63, w = tid >> 6;
  int tb = blockIdx.x;   // 16 t-tiles of 256
  int cb = blockIdx.y;   // 4 c-chunks of 128
  int b  = blockIdx.z;
  int t0 = tb * 256;
  if (tid < 128) {
    int c = cb * 128 + tid;
    float sc = bng[c] * rsqrtf(bnv[c] + 1e-5f);
    psc[tid] = sc;
    pbi[tid] = bnb[c] - bnm[c] * sc;
    pq0[tid] = dw[3 * c];
    pq1[tid] = dw[3 * c + 1];
    pq2[tid] = dw[3 * c + 2];
  }
  float alpha = pa[0];
  __syncthreads();

  int t = t0 + 4 * l;
  bool full = (t + 3 < T_);          // lanes are either fully valid or fully out
  bool has_l = (t0 > 0);
  bool has_r = (t0 + 256 < T_);
  float sum = 0.f, sq = 0.f;
  int cs_x = (l & 7) << 3;           // swizzle term (t>>2 == l for all 4 outputs)

#pragma unroll 2
  for (int i = 0; i < 16; ++i) {
    int cl = w * 16 + i;
    const float* xr = x + ((size_t)b * C_ + cb * 128 + cl) * T_;
    float sc = psc[cl], bi = pbi[cl];
    float w0 = pq0[cl], w1 = pq1[cl], w2 = pq2[cl];
    f32x4 u;
    if (full) {
      const f32x4 v = *(const f32x4*)(xr + t);
      u.x = fmaxf(v.x, 0.f) * sc + bi;
      u.y = fmaxf(v.y, 0.f) * sc + bi;
      u.z = fmaxf(v.z, 0.f) * sc + bi;
      u.w = fmaxf(v.w, 0.f) * sc + bi;
    } else {
      u = (f32x4){0.f, 0.f, 0.f, 0.f};
    }
    float el = has_l ? (fmaxf(xr[t0 - 1], 0.f) * sc + bi) : 0.f;   // uniform addr
    float er = has_r ? (fmaxf(xr[t0 + 256], 0.f) * sc + bi) : 0.f; // uniform addr
    float up = __shfl_up(u.w, 1);   if (l == 0)  up = el;
    float un = __shfl_down(u.x, 1); if (l == 63) un = er;
    float h[4];
    h[0] = w0 * up  + w1 * u.x + w2 * u.y;
    h[1] = w0 * u.x + w1 * u.y + w2 * u.z;
    h[2] = w0 * u.y + w1 * u.z + w2 * u.w;
    h[3] = w0 * u.z + w1 * u.w + w2 * un;
    int cs = cl ^ cs_x;
#pragma unroll
    for (int j = 0; j < 4; ++j) {
      float p = h[j] >= 0.f ? h[j] : alpha * h[j];
      if (!full) p = 0.f;            // t >= 4000 rows stay exactly zero
      sum += p; sq += p * p;
      hs[(4 * l + j) * 128 + cs] = f2b(p);
    }
  }

  for (int s = 32; s > 0; s >>= 1) { sum += __shfl_down(sum, s); sq += __shfl_down(sq, s); }
  if (l == 0) { partial[w] = sum; partial[8 + w] = sq; }
  __syncthreads();
  if (tid == 0) {
    float a = 0.f, c2 = 0.f;
    for (int k = 0; k < 8; ++k) { a += partial[k]; c2 += partial[8 + k]; }
    atomicAdd(&wsf[b], a);
    atomicAdd(&wsf[16 + b], c2);
  }

  // LDS tile -> global hT[b][t0+tl][cb*128 + g*8], un-swizzled, 16B/thread/pass
  unsigned short* dstb = hT + ((size_t)b * TPAD + t0) * 512 + cb * 128;
#pragma unroll
  for (int p = 0; p < 8; ++p) {
    int idx = p * 512 + tid;
    int tl = idx >> 4, g = idx & 15;
    int gs = g ^ ((tl >> 2) & 7);
    uint4 val = *(const uint4*)(hs + tl * 128 + gs * 8);
    *(uint4*)(dstb + (size_t)tl * 512 + g * 8) = val;
  }
}

__global__ void k_finalize(float* wsf) {
  int b = threadIdx.x;
  if (b < 16) {
    float n = (float)C_ * (float)T_;
    float mean = wsf[b] / n;
    float var = wsf[16 + b] / n - mean * mean;
    wsf[32 + b] = mean;
    wsf[48 + b] = rsqrtf(fmaxf(var, 0.f) + 1e-8f);
  }
}

// GEMM: out[b,o,t] = rstd[b]*sum_c W'[o,c]*h[b,c,t] + (s2[o]-mean*rstd*s1[o]) + x[b,o,t]
// 128x128 tile, BK=64, 4 waves (2x2), single 32KB LDS buffer, T2 XOR swizzle,
// global_load_lds w16 staging with pre-swizzled global source.
__global__ __launch_bounds__(256) void k_gemm(const unsigned short* __restrict__ Wp,
    const unsigned short* __restrict__ hT, const float* __restrict__ x,
    const float* __restrict__ wsf, float* __restrict__ out) {
  __shared__ unsigned short As[128 * 64];   // [o][k] swizzled, 16 KB
  __shared__ unsigned short Bs[128 * 64];   // [t][k] swizzled, 16 KB
  int tid = threadIdx.x;
  int l = tid & 63, w = tid >> 6;
  int nb = blockIdx.x, mb = blockIdx.y, b = blockIdx.z;
  int wm = w >> 1, wn = w & 1;
  const unsigned short* hTb = hT + (size_t)b * TPAD * 512;

  // per-thread staging source offsets (element units). LDS slot i holds
  // row=i>>3, 16B-slot s=i&7, global k-slot = s ^ (row&7)  (inverse swizzle on source)
  int aoff[4], boff[4];
#pragma unroll
  for (int r = 0; r < 4; ++r) {
    int i = r * 256 + tid;
    int row = i >> 3, s = i & 7;
    int ksl = (s ^ (row & 7)) << 3;
    aoff[r] = (mb * 128 + row) * 512 + ksl;
    boff[r] = (nb * 128 + row) * 512 + ksl;
  }

  f32x4 acc[4][4] = {};
  for (int ks = 0; ks < 8; ++ks) {
    int kofs = ks * 64;
#pragma unroll
    for (int r = 0; r < 4; ++r) {
      int i = r * 256 + tid;
      gl_lds16(Wp + aoff[r] + kofs, As + i * 8);
      gl_lds16(hTb + boff[r] + kofs, Bs + i * 8);
    }
    __syncthreads();   // drains vmcnt(0) -> staged tile visible
#pragma unroll
    for (int kk = 0; kk < 2; ++kk) {
      bf16x8 af[4], bfr[4];
#pragma unroll
      for (int fm = 0; fm < 4; ++fm) {
        int row = wm * 64 + fm * 16 + (l & 15);
        int slot = ((l >> 4) + kk * 4) ^ (row & 7);
        af[fm] = *(const bf16x8*)(As + row * 64 + slot * 8);
      }
#pragma unroll
      for (int fn = 0; fn < 4; ++fn) {
        int row = wn * 64 + fn * 16 + (l & 15);
        int slot = ((l >> 4) + kk * 4) ^ (row & 7);
        bfr[fn] = *(const bf16x8*)(Bs + row * 64 + slot * 8);
      }
#pragma unroll
      for (int fm = 0; fm < 4; ++fm)
#pragma unroll
        for (int fn = 0; fn < 4; ++fn)
          acc[fm][fn] = __builtin_amdgcn_mfma_f32_16x16x32_bf16(af[fm], bfr[fn], acc[fm][fn], 0, 0, 0);
    }
    __syncthreads();   // all waves done reading before next stage overwrites
  }

  float mean = wsf[32 + b], rstd = wsf[48 + b];
  float mr = mean * rstd;
#pragma unroll
  for (int fm = 0; fm < 4; ++fm) {
    int o0 = mb * 128 + wm * 64 + fm * 16 + ((l >> 4) << 2);
    float bias[4];
#pragma unroll
    for (int j = 0; j < 4; ++j) {
      int o = o0 + j;
      bias[j] = wsf[576 + o] - mr * wsf[64 + o];
    }
#pragma unroll
    for (int fn = 0; fn < 4; ++fn) {
      int t = nb * 128 + wn * 64 + fn * 16 + (l & 15);
      if (t < T_) {
#pragma unroll
        for (int j = 0; j < 4; ++j) {
          int o = o0 + j;
          size_t idx = ((size_t)b * C_ + o) * T_ + t;
          out[idx] = rstd * acc[fm][fn][j] + bias[j] + x[idx];
        }
      }
    }
  }
}

extern "C" void kernel_launch(void* const* d_in, const int* in_sizes, int n_in,
                              void* d_out, int out_size, void* d_ws, size_t ws_size,
                              hipStream_t stream) {
  const float* x   = (const float*)d_in[0];
  const float* bng = (const float*)d_in[1];
  const float* bnb = (const float*)d_in[2];
  const float* bnm = (const float*)d_in[3];
  const float* bnv = (const float*)d_in[4];
  const float* dw  = (const float*)d_in[5];
  const float* pa  = (const float*)d_in[6];
  const float* gg  = (const float*)d_in[7];
  const float* gb  = (const float*)d_in[8];
  const float* pw  = (const float*)d_in[9];
  float* out = (float*)d_out;
  float* wsf = (float*)d_ws;
  unsigned short* Wp = (unsigned short*)((char*)d_ws + 8192);
  unsigned short* hT = (unsigned short*)((char*)d_ws + (1 << 20));

  k_init<<<dim3(1), dim3(64), 0, stream>>>(wsf);
  k_prepw<<<dim3(512), dim3(64), 0, stream>>>(pw, gg, gb, Wp, wsf);
  k_front<<<dim3(16, 4, 16), dim3(512), 0, stream>>>(x, bng, bnb, bnm, bnv, dw, pa, hT, wsf);
  k_finalize<<<dim3(1), dim3(64), 0, stream>>>(wsf);
  k_gemm<<<dim3(32, 4, 16), dim3(256), 0, stream>>>(Wp, hT, x, wsf, out);
}

// Round 3
// 153.942 us; speedup vs baseline: 2.1002x; 1.0161x over previous
//
#include <hip/hip_runtime.h>
#include <stdint.h>

// Problem constants
#define B_ 16
#define C_ 512
#define T_ 4000
#define TPAD 4096   // hT rows padded per batch so tail N-tiles read in-bounds

typedef float f32x4 __attribute__((ext_vector_type(4)));
typedef __bf16 bf16x8 __attribute__((ext_vector_type(8)));

// ---------- helpers ----------
__device__ inline unsigned short f2b(float f) {   // fp32 -> bf16 bits, RNE
  uint32_t u = __builtin_bit_cast(uint32_t, f);
  u = (u + 0x7fffu + ((u >> 16) & 1u)) >> 16;
  return (unsigned short)u;
}
__device__ inline float b2f(unsigned short h) {
  uint32_t u = ((uint32_t)h) << 16;
  return __builtin_bit_cast(float, u);
}
__device__ inline void gl_lds16(const void* g, void* s) {
  __builtin_amdgcn_global_load_lds(
      (const __attribute__((address_space(1))) uint32_t*)g,
      (__attribute__((address_space(3))) uint32_t*)s, 16, 0, 0);
}

// ws float layout: [0..15] sum, [16..31] sumsq, [32..47] mean, [48..63] rstd,
//                  [64..575] s1[o], [576..1087] s2[o]
// byte 8192  : Wp bf16 [512][512]  (pw * gln_gamma, row-major o,c)
// byte 1<<20 : hT bf16 [16][4096][512]  (t-major, c contiguous)

__global__ void k_init(float* wsf) {
  int i = threadIdx.x;
  if (i < 32) wsf[i] = 0.f;
}

// one block per output row o: W'[o,c] = pw*gamma (bf16), s1[o]=sum W', s2[o]=sum pw*beta
__global__ __launch_bounds__(64) void k_prepw(const float* __restrict__ pw,
                                              const float* __restrict__ gamma,
                                              const float* __restrict__ beta,
                                              unsigned short* __restrict__ Wp,
                                              float* __restrict__ wsf) {
  int o = blockIdx.x, l = threadIdx.x;
  float a1 = 0.f, a2 = 0.f;
  for (int j = 0; j < 8; ++j) {
    int c = j * 64 + l;
    float wv = pw[o * 512 + c];
    unsigned short wb = f2b(wv * gamma[c]);
    Wp[o * 512 + c] = wb;
    a1 += b2f(wb);              // consistent with bf16 weights used in GEMM
    a2 += wv * beta[c];
  }
  for (int s = 32; s > 0; s >>= 1) { a1 += __shfl_down(a1, s); a2 += __shfl_down(a2, s); }
  if (l == 0) { wsf[64 + o] = a1; wsf[576 + o] = a2; }
}

// fused ReLU+BN+dwconv3+PReLU; writes hT[b][t][c] bf16 (transposed) + stats.
__global__ __launch_bounds__(512) void k_front(const float* __restrict__ x,
    const float* __restrict__ bng, const float* __restrict__ bnb,
    const float* __restrict__ bnm, const float* __restrict__ bnv,
    const float* __restrict__ dw, const float* __restrict__ pa,
    unsigned short* __restrict__ hT, float* __restrict__ wsf) {
  __shared__ unsigned short hs[256 * 128] __attribute__((aligned(16)));  // 64 KB
  __shared__ float psc[128], pbi[128], pq0[128], pq1[128], pq2[128];
  __shared__ float partial[16];
  int tid = threadIdx.x;
  int l = tid & 63, w = tid >> 6;
  int tb = blockIdx.x;   // 16 t-tiles of 256
  int cb = blockIdx.y;   // 4 c-chunks of 128
  int b  = blockIdx.z;
  int t0 = tb * 256;
  if (tid < 128) {
    int c = cb * 128 + tid;
    float sc = bng[c] * rsqrtf(bnv[c] + 1e-5f);
    psc[tid] = sc;
    pbi[tid] = bnb[c] - bnm[c] * sc;
    pq0[tid] = dw[3 * c];
    pq1[tid] = dw[3 * c + 1];
    pq2[tid] = dw[3 * c + 2];
  }
  float alpha = pa[0];
  __syncthreads();

  int t = t0 + 4 * l;
  bool full = (t + 3 < T_);          // lanes are either fully valid or fully out
  bool has_l = (t0 > 0);
  bool has_r = (t0 + 256 < T_);
  float sum = 0.f, sq = 0.f;
  int cs_x = (l & 7) << 3;           // swizzle term (t>>2 == l for all 4 outputs)

#pragma unroll 2
  for (int i = 0; i < 16; ++i) {
    int cl = w * 16 + i;
    const float* xr = x + ((size_t)b * C_ + cb * 128 + cl) * T_;
    float sc = psc[cl], bi = pbi[cl];
    float w0 = pq0[cl], w1 = pq1[cl], w2 = pq2[cl];
    f32x4 u;
    if (full) {
      const f32x4 v = *(const f32x4*)(xr + t);
      u.x = fmaxf(v.x, 0.f) * sc + bi;
      u.y = fmaxf(v.y, 0.f) * sc + bi;
      u.z = fmaxf(v.z, 0.f) * sc + bi;
      u.w = fmaxf(v.w, 0.f) * sc + bi;
    } else {
      u = (f32x4){0.f, 0.f, 0.f, 0.f};
    }
    float el = has_l ? (fmaxf(xr[t0 - 1], 0.f) * sc + bi) : 0.f;   // uniform addr
    float er = has_r ? (fmaxf(xr[t0 + 256], 0.f) * sc + bi) : 0.f; // uniform addr
    float up = __shfl_up(u.w, 1);   if (l == 0)  up = el;
    float un = __shfl_down(u.x, 1); if (l == 63) un = er;
    float h[4];
    h[0] = w0 * up  + w1 * u.x + w2 * u.y;
    h[1] = w0 * u.x + w1 * u.y + w2 * u.z;
    h[2] = w0 * u.y + w1 * u.z + w2 * u.w;
    h[3] = w0 * u.z + w1 * u.w + w2 * un;
    int cs = cl ^ cs_x;
#pragma unroll
    for (int j = 0; j < 4; ++j) {
      float p = h[j] >= 0.f ? h[j] : alpha * h[j];
      if (!full) p = 0.f;            // t >= 4000 rows stay exactly zero
      sum += p; sq += p * p;
      hs[(4 * l + j) * 128 + cs] = f2b(p);
    }
  }

  for (int s = 32; s > 0; s >>= 1) { sum += __shfl_down(sum, s); sq += __shfl_down(sq, s); }
  if (l == 0) { partial[w] = sum; partial[8 + w] = sq; }
  __syncthreads();
  if (tid == 0) {
    float a = 0.f, c2 = 0.f;
    for (int k = 0; k < 8; ++k) { a += partial[k]; c2 += partial[8 + k]; }
    atomicAdd(&wsf[b], a);
    atomicAdd(&wsf[16 + b], c2);
  }

  // LDS tile -> global hT[b][t0+tl][cb*128 + g*8], un-swizzled, 16B/thread/pass
  unsigned short* dstb = hT + ((size_t)b * TPAD + t0) * 512 + cb * 128;
#pragma unroll
  for (int p = 0; p < 8; ++p) {
    int idx = p * 512 + tid;
    int tl = idx >> 4, g = idx & 15;
    int gs = g ^ ((tl >> 2) & 7);
    uint4 val = *(const uint4*)(hs + tl * 128 + gs * 8);
    *(uint4*)(dstb + (size_t)tl * 512 + g * 8) = val;
  }
}

__global__ void k_finalize(float* wsf) {
  int b = threadIdx.x;
  if (b < 16) {
    float n = (float)C_ * (float)T_;
    float mean = wsf[b] / n;
    float var = wsf[16 + b] / n - mean * mean;
    wsf[32 + b] = mean;
    wsf[48 + b] = rsqrtf(fmaxf(var, 0.f) + 1e-8f);
  }
}

// GEMM v2: out[b,o,t] = rstd*sum_c W'[o,c]*h[b,c,t] + (s2[o]-mean*rstd*s1[o]) + x
// 256x256 tile, BK=32, 8 waves (2M x 4N), double-buffered 64KB LDS,
// 2-phase pipeline: issue next-tile global_load_lds BEFORE current ds_read+MFMA,
// single vmcnt(0)+barrier (from __syncthreads) AFTER the MFMA cluster.
// Swizzle: 16B slot s (0..3) of row r stores global k-slot s ^ ((r>>1)&3);
// ds_read frag addressing applies the same XOR -> 2-way-only bank aliasing.
__global__ __launch_bounds__(512, 2) void k_gemm(const unsigned short* __restrict__ Wp,
    const unsigned short* __restrict__ hT, const float* __restrict__ x,
    const float* __restrict__ wsf, float* __restrict__ out) {
  __shared__ unsigned short As0[8192], As1[8192], Bs0[8192], Bs1[8192];  // 64 KB
  int tid = threadIdx.x;
  int l = tid & 63, w = tid >> 6;
  int nb = blockIdx.x, mb = blockIdx.y, b = blockIdx.z;
  int wm = w >> 2, wn = w & 3;       // 2 x 4 wave grid; per-wave 128 o x 64 t
  const unsigned short* hTb = hT + (size_t)b * TPAD * 512;

  // staging source offsets (element units), inverse-swizzled k-slot
  int aoff[2], boff[2], ldso[2];
#pragma unroll
  for (int r = 0; r < 2; ++r) {
    int i = r * 512 + tid;           // 16B-unit index, 0..1023 (256 rows x 4 slots)
    int row = i >> 2, s = i & 3;
    int ksl = (s ^ ((row >> 1) & 3)) << 3;
    aoff[r] = (mb * 256 + row) * 512 + ksl;
    boff[r] = (nb * 256 + row) * 512 + ksl;
    ldso[r] = i * 8;                 // element offset in LDS panel
  }

  // ds_read fragment offsets (element units)
  int aro[8], bro[4];
#pragma unroll
  for (int fm = 0; fm < 8; ++fm) {
    int row = wm * 128 + fm * 16 + (l & 15);
    int slot = (l >> 4) ^ ((row >> 1) & 3);
    aro[fm] = row * 32 + slot * 8;
  }
#pragma unroll
  for (int fn = 0; fn < 4; ++fn) {
    int row = wn * 64 + fn * 16 + (l & 15);
    int slot = (l >> 4) ^ ((row >> 1) & 3);
    bro[fn] = row * 32 + slot * 8;
  }

  const unsigned short *cA = As0, *cB = Bs0;   // compute buffers
  unsigned short *nA = As1, *nB = Bs1;         // stage-target buffers

  // prologue: stage K-tile 0 into buffer 0
#pragma unroll
  for (int r = 0; r < 2; ++r) {
    gl_lds16(Wp + aoff[r], As0 + ldso[r]);
    gl_lds16(hTb + boff[r], Bs0 + ldso[r]);
  }
  __syncthreads();                   // drains vmcnt(0) -> tile 0 visible

  f32x4 acc[8][4] = {};
#pragma unroll 1
  for (int kt = 0; kt < 16; ++kt) {
    if (kt < 15) {                   // issue next-tile loads FIRST (they fly under MFMA)
      int kofs = (kt + 1) * 32;
#pragma unroll
      for (int r = 0; r < 2; ++r) {
        gl_lds16(Wp + aoff[r] + kofs, nA + ldso[r]);
        gl_lds16(hTb + boff[r] + kofs, nB + ldso[r]);
      }
    }
    bf16x8 af[8], bfv[4];
#pragma unroll
    for (int fm = 0; fm < 8; ++fm) af[fm] = *(const bf16x8*)(cA + aro[fm]);
#pragma unroll
    for (int fn = 0; fn < 4; ++fn) bfv[fn] = *(const bf16x8*)(cB + bro[fn]);
    __builtin_amdgcn_s_setprio(1);
#pragma unroll
    for (int fm = 0; fm < 8; ++fm)
#pragma unroll
      for (int fn = 0; fn < 4; ++fn)
        acc[fm][fn] = __builtin_amdgcn_mfma_f32_16x16x32_bf16(af[fm], bfv[fn], acc[fm][fn], 0, 0, 0);
    __builtin_amdgcn_s_setprio(0);
    __syncthreads();                 // vmcnt(0)+lgkmcnt(0)+barrier: staged tile ready
    const unsigned short* t1 = cA; cA = nA; nA = (unsigned short*)t1;
    const unsigned short* t2 = cB; cB = nB; nB = (unsigned short*)t2;
  }

  float mean = wsf[32 + b], rstd = wsf[48 + b];
  float mr = mean * rstd;
#pragma unroll
  for (int fm = 0; fm < 8; ++fm) {
    int o0 = mb * 256 + wm * 128 + fm * 16 + ((l >> 4) << 2);
    float bias[4];
#pragma unroll
    for (int j = 0; j < 4; ++j) {
      int o = o0 + j;
      bias[j] = wsf[576 + o] - mr * wsf[64 + o];
    }
#pragma unroll
    for (int fn = 0; fn < 4; ++fn) {
      int t = nb * 256 + wn * 64 + fn * 16 + (l & 15);
      if (t < T_) {
#pragma unroll
        for (int j = 0; j < 4; ++j) {
          int o = o0 + j;
          size_t idx = ((size_t)b * C_ + o) * T_ + t;
          out[idx] = rstd * acc[fm][fn][j] + bias[j] + x[idx];
        }
      }
    }
  }
}

extern "C" void kernel_launch(void* const* d_in, const int* in_sizes, int n_in,
                              void* d_out, int out_size, void* d_ws, size_t ws_size,
                              hipStream_t stream) {
  const float* x   = (const float*)d_in[0];
  const float* bng = (const float*)d_in[1];
  const float* bnb = (const float*)d_in[2];
  const float* bnm = (const float*)d_in[3];
  const float* bnv = (const float*)d_in[4];
  const float* dw  = (const float*)d_in[5];
  const float* pa  = (const float*)d_in[6];
  const float* gg  = (const float*)d_in[7];
  const float* gb  = (const float*)d_in[8];
  const float* pw  = (const float*)d_in[9];
  float* out = (float*)d_out;
  float* wsf = (float*)d_ws;
  unsigned short* Wp = (unsigned short*)((char*)d_ws + 8192);
  unsigned short* hT = (unsigned short*)((char*)d_ws + (1 << 20));

  k_init<<<dim3(1), dim3(64), 0, stream>>>(wsf);
  k_prepw<<<dim3(512), dim3(64), 0, stream>>>(pw, gg, gb, Wp, wsf);
  k_front<<<dim3(16, 4, 16), dim3(512), 0, stream>>>(x, bng, bnb, bnm, bnv, dw, pa, hT, wsf);
  k_finalize<<<dim3(1), dim3(64), 0, stream>>>(wsf);
  k_gemm<<<dim3(16, 2, 16), dim3(512), 0, stream>>>(Wp, hT, x, wsf, out);
}